// Round 7
// baseline (440.725 us; speedup 1.0000x reference)
//
#include <hip/hip_runtime.h>
#include <hip/hip_fp16.h>

#define IN_F 512
#define OH   512   // OUT*H
#define NH   8     // heads

typedef _Float16 half_t;
typedef __attribute__((ext_vector_type(8))) _Float16 f16x8;
typedef __attribute__((ext_vector_type(4))) float    f32x4;

// ---------------------------------------------------------------------------
// cast f32 -> f16 for W only (1 MB -> 0.5 MB, ~3 us)
// ---------------------------------------------------------------------------
__global__ __launch_bounds__(256) void k_castW(const float* __restrict__ W,
                                               half_t* __restrict__ Wh, int n) {
  int i = (blockIdx.x * 256 + threadIdx.x) * 8;
  if (i >= n) return;
  float4 a = *(const float4*)(W + i);
  float4 b = *(const float4*)(W + i + 4);
  f16x8 h;
  h[0] = (half_t)a.x; h[1] = (half_t)a.y; h[2] = (half_t)a.z; h[3] = (half_t)a.w;
  h[4] = (half_t)b.x; h[5] = (half_t)b.y; h[6] = (half_t)b.z; h[7] = (half_t)b.w;
  *(f16x8*)(Wh + i) = h;
}

// ---------------------------------------------------------------------------
// Zero-LDS direct-to-register MFMA GEMM.
// Block = 128 rows x 128 cols, 4 waves (2x2), each wave owns a 64x64 tile.
// Per K-step (BK=32) per lane: 8 f32x4 A-loads (16 rows x 128B contiguous per
// frag-load -> coalesced), 4 f16x8 B-loads (W is L2-resident), cvt, 16 MFMA.
// No LDS, no barriers -> no lockstep stalls; compiler pipelines loads across
// K-steps freely.  XCD swizzle keeps the X col-block re-reads L2-local.
// Epilogue: Zh write + fused per-head el/er atomic partials.
// ---------------------------------------------------------------------------
__global__ __launch_bounds__(256) void k_gemm_direct(const float* __restrict__ X,
                                                     const half_t* __restrict__ Wh,
                                                     const float* __restrict__ bias,
                                                     const float* __restrict__ al,
                                                     const float* __restrict__ ar,
                                                     half_t* __restrict__ Zh,
                                                     float* __restrict__ el,
                                                     float* __restrict__ er,
                                                     int N, int nwg) {
  const int tid  = threadIdx.x;
  const int lane = tid & 63;
  const int wid  = tid >> 6;
  const int wr = wid >> 1, wc = wid & 1;

  // bijective XCD swizzle (m204)
  int orig = blockIdx.x;
  int xcd = orig & 7;
  int q = nwg >> 3, r = nwg & 7;
  int start = (xcd < r) ? xcd * (q + 1) : r * (q + 1) + (xcd - r) * q;
  int work = start + (orig >> 3);
  const int n0 = (work >> 2) * 128;
  const int j0 = (work & 3) * 128;

  const int rl = lane & 15;
  const int hi16 = lane >> 4;
  const int kg = hi16 * 8;     // k-offset within BK=32

  f32x4 acc[4][4] = {};

  // per-lane fragment base pointers (kt-invariant)
  const float*  aptr[4];
  const half_t* bptr[4];
#pragma unroll
  for (int m = 0; m < 4; m++) {
    int rA = n0 + wr * 64 + m * 16 + rl; if (rA >= N) rA = N - 1;
    aptr[m] = X + (size_t)rA * IN_F + kg;
    int rB = j0 + wc * 64 + m * 16 + rl;
    bptr[m] = Wh + (size_t)rB * IN_F + kg;
  }

#pragma unroll 4
  for (int kt = 0; kt < IN_F; kt += 32) {
    f16x8 af[4], bf[4];
#pragma unroll
    for (int m = 0; m < 4; m++) {
      f32x4 lo = *(const f32x4*)(aptr[m] + kt);
      f32x4 hi = *(const f32x4*)(aptr[m] + kt + 4);
      f16x8 a;
#pragma unroll
      for (int u = 0; u < 4; u++) { a[u] = (half_t)lo[u]; a[u + 4] = (half_t)hi[u]; }
      af[m] = a;
      bf[m] = *(const f16x8*)(bptr[m] + kt);
    }
#pragma unroll
    for (int m = 0; m < 4; m++)
#pragma unroll
      for (int n = 0; n < 4; n++)
        acc[m][n] = __builtin_amdgcn_mfma_f32_16x16x32_f16(af[m], bf[n], acc[m][n], 0, 0, 0);
  }

  // ---- epilogue: Zh write + per-head el/er partials ----
  // C/D layout: col=lane&15, row=(lane>>4)*4+q.  Lane's head h = rl & 7.
  float partl[4][4], partr[4][4];
#pragma unroll
  for (int m = 0; m < 4; m++)
#pragma unroll
    for (int qq = 0; qq < 4; qq++) { partl[m][qq] = 0.f; partr[m][qq] = 0.f; }

#pragma unroll
  for (int n = 0; n < 4; n++) {
    int j = j0 + wc * 64 + n * 16 + rl;
    float bv = bias[j];
    float av = al[j];
    float rv = ar[j];
#pragma unroll
    for (int m = 0; m < 4; m++) {
      int rbase = n0 + wr * 64 + m * 16 + hi16 * 4;
#pragma unroll
      for (int qq = 0; qq < 4; qq++) {
        float v = acc[m][n][qq] + bv;
        int nrow = rbase + qq;
        if (nrow < N) Zh[(size_t)nrow * OH + j] = (half_t)v;
        partl[m][qq] = fmaf(v, av, partl[m][qq]);
        partr[m][qq] = fmaf(v, rv, partr[m][qq]);
      }
    }
  }
  const int h = rl & 7;
#pragma unroll
  for (int m = 0; m < 4; m++) {
#pragma unroll
    for (int qq = 0; qq < 4; qq++) {
      float pl = partl[m][qq], pr = partr[m][qq];
      pl += __shfl_xor(pl, 8);    // fold rl and rl+8 (same head)
      pr += __shfl_xor(pr, 8);
      if (rl < 8) {
        int nrow = n0 + wr * 64 + m * 16 + hi16 * 4 + qq;
        if (nrow < N) {
          atomicAdd(&el[(size_t)nrow * NH + h], pl);
          atomicAdd(&er[(size_t)nrow * NH + h], pr);
        }
      }
    }
  }
}

// ---------------------------------------------------------------------------
// CSR build
// ---------------------------------------------------------------------------
__global__ void k_hist(const int* __restrict__ row, int* __restrict__ deg, int E) {
  int e = blockIdx.x * blockDim.x + threadIdx.x;
  if (e < E) atomicAdd(&deg[row[e]], 1);
}

#define SCAN_B 1024
__global__ __launch_bounds__(SCAN_B) void k_scan1(const int* __restrict__ deg,
                                                  int* __restrict__ off,
                                                  int* __restrict__ sums, int N) {
  __shared__ int s[SCAN_B];
  int tid = threadIdx.x;
  int g = blockIdx.x * SCAN_B + tid;
  int v = (g < N) ? deg[g] : 0;
  s[tid] = v;
  __syncthreads();
  for (int o = 1; o < SCAN_B; o <<= 1) {
    int t = (tid >= o) ? s[tid - o] : 0;
    __syncthreads();
    s[tid] += t;
    __syncthreads();
  }
  if (g < N) off[g] = s[tid] - v;
  if (tid == SCAN_B - 1) sums[blockIdx.x] = s[tid];
}

__global__ __launch_bounds__(SCAN_B) void k_scan3(int* __restrict__ off,
                                                  int* __restrict__ cursor,
                                                  const int* __restrict__ sums,
                                                  int nb, int N, int E) {
  __shared__ int sboff;
  int tid = threadIdx.x;
  if (tid < 64) {
    int v = (tid < nb && tid < (int)blockIdx.x) ? sums[tid] : 0;
#pragma unroll
    for (int s = 1; s < 64; s <<= 1) v += __shfl_xor(v, s);
    if (tid == 0) sboff = v;
  }
  __syncthreads();
  int g = blockIdx.x * SCAN_B + tid;
  if (g < N) {
    int v = off[g] + sboff;
    off[g] = v;
    cursor[g] = v;
  }
  if (g == 0) off[N] = E;
}

__global__ void k_fill(const int* __restrict__ row, const int* __restrict__ col,
                       int* __restrict__ cursor, int* __restrict__ colS, int E) {
  int e = blockIdx.x * blockDim.x + threadIdx.x;
  if (e < E) {
    int r = row[e];
    int p = atomicAdd(&cursor[r], 1);
    colS[p] = col[e];
  }
}

// ---------------------------------------------------------------------------
// Fused edge-softmax + aggregation.  NT store for `out` (streamed once, keep
// L3 for Zh); NT load for colS (single-use stream).
// ---------------------------------------------------------------------------
__global__ __launch_bounds__(256) void k_attagg(const half_t* __restrict__ Zh,
                                                const float* __restrict__ el,
                                                const float* __restrict__ er,
                                                const int* __restrict__ off,
                                                const int* __restrict__ colS,
                                                float* __restrict__ out, int N) {
  __shared__ float wts[4][64][NH];   // 8 KB
  __shared__ int   cls[4][64];       // 1 KB
  int wid = threadIdx.x >> 6, lane = threadIdx.x & 63;
  int i = blockIdx.x * 4 + wid;
  if (i >= N) return;
  int s = off[i], t = off[i + 1];
  int deg = t - s;

  float eli[8];
  {
    const float4* e4 = (const float4*)(el + (size_t)i * NH);
    float4 a = e4[0], b = e4[1];
    eli[0] = a.x; eli[1] = a.y; eli[2] = a.z; eli[3] = a.w;
    eli[4] = b.x; eli[5] = b.y; eli[6] = b.z; eli[7] = b.w;
  }

  float m[8], ehs[8];
  int csave = 0;
#pragma unroll
  for (int h = 0; h < 8; h++) m[h] = -1e30f;
  for (int p = s + lane; p < t; p += 64) {
    int c = __builtin_nontemporal_load(&colS[p]);
    csave = c;
    const float4* e4 = (const float4*)(er + (size_t)c * NH);
    float4 ea = e4[0], eb = e4[1];
    float ev[8] = {ea.x, ea.y, ea.z, ea.w, eb.x, eb.y, eb.z, eb.w};
#pragma unroll
    for (int h = 0; h < 8; h++) {
      float eh = eli[h] + ev[h];
      eh = (eh > 0.f) ? eh : 0.01f * eh;
      ehs[h] = eh;
      m[h] = fmaxf(m[h], eh);
    }
  }
#pragma unroll
  for (int st = 1; st < 64; st <<= 1)
#pragma unroll
    for (int h = 0; h < 8; h++) m[h] = fmaxf(m[h], __shfl_xor(m[h], st));

  float acc[8], den[8];
#pragma unroll
  for (int h = 0; h < 8; h++) { acc[h] = 0.f; den[h] = 0.f; }

  for (int base = s; base < t; base += 64) {
    int p = base + lane;
    if (p < t) {
      int c;
      float eh[8];
      if (deg <= 64) {
        c = csave;
#pragma unroll
        for (int h = 0; h < 8; h++) eh[h] = ehs[h];
      } else {
        c = __builtin_nontemporal_load(&colS[p]);
        const float4* e4 = (const float4*)(er + (size_t)c * NH);
        float4 ea = e4[0], eb = e4[1];
        float ev[8] = {ea.x, ea.y, ea.z, ea.w, eb.x, eb.y, eb.z, eb.w};
#pragma unroll
        for (int h = 0; h < 8; h++) {
          float e2 = eli[h] + ev[h];
          eh[h] = (e2 > 0.f) ? e2 : 0.01f * e2;
        }
      }
      cls[wid][lane] = c;
#pragma unroll
      for (int h = 0; h < 8; h++) {
        float pr = __expf(eh[h] - m[h]);
        den[h] += pr;
        wts[wid][lane][h] = pr;
      }
    }
    int cnt = t - base; if (cnt > 64) cnt = 64;

    int e = 0;
    for (; e + 4 <= cnt; e += 4) {
      int c0 = cls[wid][e + 0], c1 = cls[wid][e + 1];
      int c2 = cls[wid][e + 2], c3 = cls[wid][e + 3];
      f16x8 z0 = *(const f16x8*)(Zh + (size_t)c0 * OH + lane * 8);
      f16x8 z1 = *(const f16x8*)(Zh + (size_t)c1 * OH + lane * 8);
      f16x8 z2 = *(const f16x8*)(Zh + (size_t)c2 * OH + lane * 8);
      f16x8 z3 = *(const f16x8*)(Zh + (size_t)c3 * OH + lane * 8);
      const float* w0 = &wts[wid][e + 0][0];
      const float* w1 = &wts[wid][e + 1][0];
      const float* w2 = &wts[wid][e + 2][0];
      const float* w3 = &wts[wid][e + 3][0];
#pragma unroll
      for (int h = 0; h < 8; h++) {
        acc[h] = fmaf(w0[h], (float)z0[h], acc[h]);
        acc[h] = fmaf(w1[h], (float)z1[h], acc[h]);
        acc[h] = fmaf(w2[h], (float)z2[h], acc[h]);
        acc[h] = fmaf(w3[h], (float)z3[h], acc[h]);
      }
    }
    for (; e < cnt; e++) {
      int c = cls[wid][e];
      f16x8 z = *(const f16x8*)(Zh + (size_t)c * OH + lane * 8);
      const float* w = &wts[wid][e][0];
#pragma unroll
      for (int h = 0; h < 8; h++) acc[h] = fmaf(w[h], (float)z[h], acc[h]);
    }
  }

#pragma unroll
  for (int st = 1; st < 64; st <<= 1)
#pragma unroll
    for (int h = 0; h < 8; h++) den[h] += __shfl_xor(den[h], st);

  f32x4 o0, o1;
  o0[0] = acc[0] / den[0]; o0[1] = acc[1] / den[1];
  o0[2] = acc[2] / den[2]; o0[3] = acc[3] / den[3];
  o1[0] = acc[4] / den[4]; o1[1] = acc[5] / den[5];
  o1[2] = acc[6] / den[6]; o1[3] = acc[7] / den[7];
  __builtin_nontemporal_store(o0, (f32x4*)(out + (size_t)i * OH + lane * 8));
  __builtin_nontemporal_store(o1, (f32x4*)(out + (size_t)i * OH + lane * 8 + 4));
}

// ---------------------------------------------------------------------------
extern "C" void kernel_launch(void* const* d_in, const int* in_sizes, int n_in,
                              void* d_out, int out_size, void* d_ws, size_t ws_size,
                              hipStream_t stream) {
  const float* X    = (const float*)d_in[0];
  const float* W    = (const float*)d_in[1];
  const float* bias = (const float*)d_in[2];
  const float* a_l  = (const float*)d_in[3];
  const float* a_r  = (const float*)d_in[4];
  const int*   row  = (const int*)d_in[5];
  const int*   col  = (const int*)d_in[6];
  float* out = (float*)d_out;

  const int N = in_sizes[0] / IN_F;   // 50000
  const int E = in_sizes[5];          // 850000
  const int nWe = OH * IN_F;

  auto align_up = [](size_t v) { return (v + 255) & ~(size_t)255; };
  char* p = (char*)d_ws;
  half_t* Wh    = (half_t*)p; p += align_up((size_t)nWe * 2);
  half_t* Zh    = (half_t*)p; p += align_up((size_t)N * OH * 2);
  float* el     = (float*)p;  p += (size_t)N * NH * 4;        // el/er contiguous
  float* er     = (float*)p;  p += align_up((size_t)N * NH * 4);
  int*   deg    = (int*)p;    p += align_up((size_t)N * 4);
  int*   off    = (int*)p;    p += align_up((size_t)(N + 1) * 4);
  int*   cursor = (int*)p;    p += align_up((size_t)N * 4);
  int*   sums   = (int*)p;    p += align_up((size_t)64 * 4);
  int*   colS   = (int*)p;    p += align_up((size_t)E * 4);
  (void)ws_size; (void)n_in; (void)out_size;

  const int nb = (N + SCAN_B - 1) / SCAN_B;

  hipMemsetAsync(deg, 0, (size_t)N * 4, stream);
  hipMemsetAsync(el, 0, (size_t)2 * N * NH * 4, stream);

  hipLaunchKernelGGL(k_castW, dim3((nWe / 8 + 255) / 256), dim3(256), 0, stream,
                     W, Wh, nWe);

  // zero-LDS direct-register MFMA GEMM + el/er epilogue
  const int nwg = ((N + 127) / 128) * 4;
  hipLaunchKernelGGL(k_gemm_direct, dim3(nwg), dim3(256), 0, stream,
                     X, Wh, bias, a_l, a_r, Zh, el, er, N, nwg);

  // CSR build
  hipLaunchKernelGGL(k_hist, dim3((E + 255) / 256), dim3(256), 0, stream, row, deg, E);
  hipLaunchKernelGGL(k_scan1, dim3(nb), dim3(SCAN_B), 0, stream, deg, off, sums, N);
  hipLaunchKernelGGL(k_scan3, dim3(nb), dim3(SCAN_B), 0, stream,
                     off, cursor, sums, nb, N, E);
  hipLaunchKernelGGL(k_fill, dim3((E + 255) / 256), dim3(256), 0, stream,
                     row, col, cursor, colS, E);

  // fused softmax + aggregation
  hipLaunchKernelGGL(k_attagg, dim3((N + 3) / 4), dim3(256), 0, stream,
                     Zh, el, er, off, colS, out, N);
}

// Round 8
// 346.052 us; speedup vs baseline: 1.2736x; 1.2736x over previous
//
#include <hip/hip_runtime.h>
#include <hip/hip_fp16.h>

#define IN_F 512
#define OH   512   // OUT*H
#define NH   8     // heads

typedef _Float16 half_t;
typedef __attribute__((ext_vector_type(8))) _Float16 f16x8;
typedef __attribute__((ext_vector_type(4))) float    f32x4;

#define GLOBAL_AS const __attribute__((address_space(1))) void
#define LDS_AS    __attribute__((address_space(3))) void

__device__ static inline void gload_lds16(const void* g, void* l) {
  __builtin_amdgcn_global_load_lds((GLOBAL_AS*)g, (LDS_AS*)l, 16, 0, 0);
}
#define MEMBAR asm volatile("" ::: "memory")

// ---------------------------------------------------------------------------
// cast f32 -> f16 for W only
// ---------------------------------------------------------------------------
__global__ __launch_bounds__(256) void k_castW(const float* __restrict__ W,
                                               half_t* __restrict__ Wh, int n) {
  int i = (blockIdx.x * 256 + threadIdx.x) * 8;
  if (i >= n) return;
  float4 a = *(const float4*)(W + i);
  float4 b = *(const float4*)(W + i + 4);
  f16x8 h;
  h[0] = (half_t)a.x; h[1] = (half_t)a.y; h[2] = (half_t)a.z; h[3] = (half_t)a.w;
  h[4] = (half_t)b.x; h[5] = (half_t)b.y; h[6] = (half_t)b.z; h[7] = (half_t)b.w;
  *(f16x8*)(Wh + i) = h;
}

// ---------------------------------------------------------------------------
// MFMA f16 GEMM v5: 128x128 tile, 4 waves, BK=32, double-buffered, counted
// vmcnt pipeline (T3/T4).  A: reg-staged depth-2 (f32 global -> cvt -> ds_write
// into padded [128][40] f16 LDS: fragment reads bank-conflict-free).
// B: global_load_lds depth-1 with pre-swizzled global granules (read slot =
// hi16 ^ (row&3)).  Per iter issue [B(k+1) x2, A(k+2) x4]; vmcnt(4) ->
// A(k+1) regs + B(k+1) LDS complete; one lgkmcnt(0)+s_barrier per iter.
// Epilogue: Zh write + fused per-head el/er atomic partials.
// ---------------------------------------------------------------------------
__global__ __launch_bounds__(256) void k_gemm16_v5(const float* __restrict__ X,
                                                   const half_t* __restrict__ Wh,
                                                   const float* __restrict__ bias,
                                                   const float* __restrict__ al,
                                                   const float* __restrict__ ar,
                                                   half_t* __restrict__ Zh,
                                                   float* __restrict__ el,
                                                   float* __restrict__ er,
                                                   int N, int nwg) {
  __shared__ half_t Asw[2][128][40];   // 2 x 10 KB (padded: row stride 80B)
  __shared__ half_t Bs[2][128][32];    // 2 x 8 KB
  const int tid  = threadIdx.x;
  const int lane = tid & 63;
  const int wid  = tid >> 6;
  const int wr = wid >> 1, wc = wid & 1;

  // bijective XCD swizzle (m204)
  int orig = blockIdx.x;
  int xcd = orig & 7;
  int q = nwg >> 3, r = nwg & 7;
  int start = (xcd < r) ? xcd * (q + 1) : r * (q + 1) + (xcd - r) * q;
  int work = start + (orig >> 3);
  const int n0 = (work >> 2) * 128;
  const int j0 = (work & 3) * 128;

  const int rl = lane & 15;
  const int hi16 = lane >> 4;

  // ---- preload epilogue coefficients, then drain vmcnt so the counted
  //      window below contains ONLY the staging loads.
  float bv[4], av[4], rv[4];
#pragma unroll
  for (int n = 0; n < 4; n++) {
    int j = j0 + wc * 64 + n * 16 + rl;
    bv[n] = bias[j]; av[n] = al[j]; rv[n] = ar[j];
  }
  asm volatile("s_waitcnt vmcnt(0)" ::: "memory");

  // ---- A staging map: thread t -> row t>>1, 16-f32 half (t&1)
  const int arow = tid >> 1;
  const int ap   = (tid & 1) << 4;         // element offset (f32 and f16 idx)
  int an = n0 + arow; if (an >= N) an = N - 1;
  const float* aSrc = X + (size_t)an * IN_F + ap;
  half_t* aDst0 = &Asw[0][arow][ap];
  half_t* aDst1 = &Asw[1][arow][ap];

  // ---- B staging map (pre-swizzled global granule)
  int b_rb[2], b_off[2];
#pragma unroll
  for (int c = 0; c < 2; c++) {
    int off = wid * 2048 + c * 1024 + lane * 16;
    int rb = off >> 6;
    int gs = (off >> 4) & 3;
    b_rb[c]  = rb;
    b_off[c] = (gs ^ (rb & 3)) << 3;       // halves
  }

#define GLOADB(BUF, KT)                                                        \
  do {                                                                         \
    _Pragma("unroll")                                                          \
    for (int c = 0; c < 2; c++) {                                              \
      const half_t* g = Wh + (size_t)(j0 + b_rb[c]) * IN_F + (KT) + b_off[c];  \
      gload_lds16(g, (char*)&Bs[BUF][0][0] + wid * 2048 + c * 1024);           \
    }                                                                          \
  } while (0)

#define CVT_WRITE(DST, R0, R1, R2, R3)                                         \
  do {                                                                         \
    f16x8 h0_, h1_;                                                            \
    _Pragma("unroll")                                                          \
    for (int u = 0; u < 4; u++) {                                              \
      h0_[u] = (half_t)R0[u]; h0_[u + 4] = (half_t)R1[u];                      \
      h1_[u] = (half_t)R2[u]; h1_[u + 4] = (half_t)R3[u];                      \
    }                                                                          \
    *(f16x8*)(DST) = h0_; *(f16x8*)((DST) + 8) = h1_;                          \
  } while (0)

  f32x4 acc[4][4] = {};

  // ---- prologue: A(0)->regs, B(0)->LDS, A(1)->regs; wait A(0)+B(0)
  f32x4 aP0 = *(const f32x4*)(aSrc + 0);
  f32x4 aP1 = *(const f32x4*)(aSrc + 4);
  f32x4 aP2 = *(const f32x4*)(aSrc + 8);
  f32x4 aP3 = *(const f32x4*)(aSrc + 12);
  MEMBAR;
  GLOADB(0, 0);
  MEMBAR;
  f32x4 aC0 = *(const f32x4*)(aSrc + 32);
  f32x4 aC1 = *(const f32x4*)(aSrc + 36);
  f32x4 aC2 = *(const f32x4*)(aSrc + 40);
  f32x4 aC3 = *(const f32x4*)(aSrc + 44);
  asm volatile("s_waitcnt vmcnt(4)" ::: "memory");   // A(0), B(0) done
  CVT_WRITE(aDst0, aP0, aP1, aP2, aP3);
  asm volatile("s_waitcnt lgkmcnt(0)" ::: "memory");
  __builtin_amdgcn_s_barrier();

#pragma unroll
  for (int ki = 0; ki < 16; ki++) {
    const int cur = ki & 1;
    // issue next-tile stages (counted)
    if (ki < 15) { GLOADB(cur ^ 1, (ki + 1) * 32); MEMBAR; }
    f32x4 aN0, aN1, aN2, aN3;
    if (ki < 14) {
      aN0 = *(const f32x4*)(aSrc + (ki + 2) * 32);
      aN1 = *(const f32x4*)(aSrc + (ki + 2) * 32 + 4);
      aN2 = *(const f32x4*)(aSrc + (ki + 2) * 32 + 8);
      aN3 = *(const f32x4*)(aSrc + (ki + 2) * 32 + 12);
      MEMBAR;
    }

    // ---- compute tile ki from LDS
    f16x8 af[4], bf[4];
#pragma unroll
    for (int m = 0; m < 4; m++) {
      int rA = wr * 64 + m * 16 + rl;
      af[m] = *(const f16x8*)((const char*)&Asw[cur][0][0] + rA * 80 + hi16 * 16);
      int rB = wc * 64 + m * 16 + rl;
      bf[m] = *(const f16x8*)((const char*)&Bs[cur][0][0] + rB * 64 +
                              (((hi16 ^ (rB & 3))) << 4));
    }
#pragma unroll
    for (int m = 0; m < 4; m++)
#pragma unroll
      for (int n = 0; n < 4; n++)
        acc[m][n] = __builtin_amdgcn_mfma_f32_16x16x32_f16(af[m], bf[n], acc[m][n], 0, 0, 0);

    if (ki < 15) {
      if (ki < 14) { asm volatile("s_waitcnt vmcnt(4)" ::: "memory"); }
      else         { asm volatile("s_waitcnt vmcnt(0)" ::: "memory"); }
      // A(ki+1) regs ready -> write into the buffer we just finished reading
      CVT_WRITE((cur == 0 ? aDst1 : aDst0), aC0, aC1, aC2, aC3);
      asm volatile("s_waitcnt lgkmcnt(0)" ::: "memory");
      __builtin_amdgcn_s_barrier();
      if (ki < 14) { aC0 = aN0; aC1 = aN1; aC2 = aN2; aC3 = aN3; }
    }
  }
#undef GLOADB
#undef CVT_WRITE

  // ---- epilogue: Zh write + per-head el/er partials ----
  // C/D layout: col=lane&15, row=(lane>>4)*4+q.  Lane's head h = rl & 7.
  float partl[4][4], partr[4][4];
#pragma unroll
  for (int m = 0; m < 4; m++)
#pragma unroll
    for (int qq = 0; qq < 4; qq++) { partl[m][qq] = 0.f; partr[m][qq] = 0.f; }

#pragma unroll
  for (int n = 0; n < 4; n++) {
    int j = j0 + wc * 64 + n * 16 + rl;
#pragma unroll
    for (int m = 0; m < 4; m++) {
      int rbase = n0 + wr * 64 + m * 16 + hi16 * 4;
#pragma unroll
      for (int qq = 0; qq < 4; qq++) {
        float v = acc[m][n][qq] + bv[n];
        int nrow = rbase + qq;
        if (nrow < N) Zh[(size_t)nrow * OH + j] = (half_t)v;
        partl[m][qq] = fmaf(v, av[n], partl[m][qq]);
        partr[m][qq] = fmaf(v, rv[n], partr[m][qq]);
      }
    }
  }
  const int h = rl & 7;
#pragma unroll
  for (int m = 0; m < 4; m++) {
#pragma unroll
    for (int qq = 0; qq < 4; qq++) {
      float pl = partl[m][qq], pr = partr[m][qq];
      pl += __shfl_xor(pl, 8);    // fold rl and rl+8 (same head)
      pr += __shfl_xor(pr, 8);
      if (rl < 8) {
        int nrow = n0 + wr * 64 + m * 16 + hi16 * 4 + qq;
        if (nrow < N) {
          atomicAdd(&el[(size_t)nrow * NH + h], pl);
          atomicAdd(&er[(size_t)nrow * NH + h], pr);
        }
      }
    }
  }
}

// ---------------------------------------------------------------------------
// CSR build
// ---------------------------------------------------------------------------
__global__ void k_hist(const int* __restrict__ row, int* __restrict__ deg, int E) {
  int e = blockIdx.x * blockDim.x + threadIdx.x;
  if (e < E) atomicAdd(&deg[row[e]], 1);
}

#define SCAN_B 1024
__global__ __launch_bounds__(SCAN_B) void k_scan1(const int* __restrict__ deg,
                                                  int* __restrict__ off,
                                                  int* __restrict__ sums, int N) {
  __shared__ int s[SCAN_B];
  int tid = threadIdx.x;
  int g = blockIdx.x * SCAN_B + tid;
  int v = (g < N) ? deg[g] : 0;
  s[tid] = v;
  __syncthreads();
  for (int o = 1; o < SCAN_B; o <<= 1) {
    int t = (tid >= o) ? s[tid - o] : 0;
    __syncthreads();
    s[tid] += t;
    __syncthreads();
  }
  if (g < N) off[g] = s[tid] - v;
  if (tid == SCAN_B - 1) sums[blockIdx.x] = s[tid];
}

__global__ __launch_bounds__(SCAN_B) void k_scan3(int* __restrict__ off,
                                                  int* __restrict__ cursor,
                                                  const int* __restrict__ sums,
                                                  int nb, int N, int E) {
  __shared__ int sboff;
  int tid = threadIdx.x;
  if (tid < 64) {
    int v = (tid < nb && tid < (int)blockIdx.x) ? sums[tid] : 0;
#pragma unroll
    for (int s = 1; s < 64; s <<= 1) v += __shfl_xor(v, s);
    if (tid == 0) sboff = v;
  }
  __syncthreads();
  int g = blockIdx.x * SCAN_B + tid;
  if (g < N) {
    int v = off[g] + sboff;
    off[g] = v;
    cursor[g] = v;
  }
  if (g == 0) off[N] = E;
}

__global__ void k_fill(const int* __restrict__ row, const int* __restrict__ col,
                       int* __restrict__ cursor, int* __restrict__ colS, int E) {
  int e = blockIdx.x * blockDim.x + threadIdx.x;
  if (e < E) {
    int r = row[e];
    int p = atomicAdd(&cursor[r], 1);
    colS[p] = col[e];
  }
}

// ---------------------------------------------------------------------------
// Fused edge-softmax + aggregation (NT store for out, NT load for colS)
// ---------------------------------------------------------------------------
__global__ __launch_bounds__(256) void k_attagg(const half_t* __restrict__ Zh,
                                                const float* __restrict__ el,
                                                const float* __restrict__ er,
                                                const int* __restrict__ off,
                                                const int* __restrict__ colS,
                                                float* __restrict__ out, int N) {
  __shared__ float wts[4][64][NH];   // 8 KB
  __shared__ int   cls[4][64];       // 1 KB
  int wid = threadIdx.x >> 6, lane = threadIdx.x & 63;
  int i = blockIdx.x * 4 + wid;
  if (i >= N) return;
  int s = off[i], t = off[i + 1];
  int deg = t - s;

  float eli[8];
  {
    const float4* e4 = (const float4*)(el + (size_t)i * NH);
    float4 a = e4[0], b = e4[1];
    eli[0] = a.x; eli[1] = a.y; eli[2] = a.z; eli[3] = a.w;
    eli[4] = b.x; eli[5] = b.y; eli[6] = b.z; eli[7] = b.w;
  }

  float m[8], ehs[8];
  int csave = 0;
#pragma unroll
  for (int h = 0; h < 8; h++) m[h] = -1e30f;
  for (int p = s + lane; p < t; p += 64) {
    int c = __builtin_nontemporal_load(&colS[p]);
    csave = c;
    const float4* e4 = (const float4*)(er + (size_t)c * NH);
    float4 ea = e4[0], eb = e4[1];
    float ev[8] = {ea.x, ea.y, ea.z, ea.w, eb.x, eb.y, eb.z, eb.w};
#pragma unroll
    for (int h = 0; h < 8; h++) {
      float eh = eli[h] + ev[h];
      eh = (eh > 0.f) ? eh : 0.01f * eh;
      ehs[h] = eh;
      m[h] = fmaxf(m[h], eh);
    }
  }
#pragma unroll
  for (int st = 1; st < 64; st <<= 1)
#pragma unroll
    for (int h = 0; h < 8; h++) m[h] = fmaxf(m[h], __shfl_xor(m[h], st));

  float acc[8], den[8];
#pragma unroll
  for (int h = 0; h < 8; h++) { acc[h] = 0.f; den[h] = 0.f; }

  for (int base = s; base < t; base += 64) {
    int p = base + lane;
    if (p < t) {
      int c;
      float eh[8];
      if (deg <= 64) {
        c = csave;
#pragma unroll
        for (int h = 0; h < 8; h++) eh[h] = ehs[h];
      } else {
        c = __builtin_nontemporal_load(&colS[p]);
        const float4* e4 = (const float4*)(er + (size_t)c * NH);
        float4 ea = e4[0], eb = e4[1];
        float ev[8] = {ea.x, ea.y, ea.z, ea.w, eb.x, eb.y, eb.z, eb.w};
#pragma unroll
        for (int h = 0; h < 8; h++) {
          float e2 = eli[h] + ev[h];
          eh[h] = (e2 > 0.f) ? e2 : 0.01f * e2;
        }
      }
      cls[wid][lane] = c;
#pragma unroll
      for (int h = 0; h < 8; h++) {
        float pr = __expf(eh[h] - m[h]);
        den[h] += pr;
        wts[wid][lane][h] = pr;
      }
    }
    int cnt = t - base; if (cnt > 64) cnt = 64;

    int e = 0;
    for (; e + 4 <= cnt; e += 4) {
      int c0 = cls[wid][e + 0], c1 = cls[wid][e + 1];
      int c2 = cls[wid][e + 2], c3 = cls[wid][e + 3];
      f16x8 z0 = *(const f16x8*)(Zh + (size_t)c0 * OH + lane * 8);
      f16x8 z1 = *(const f16x8*)(Zh + (size_t)c1 * OH + lane * 8);
      f16x8 z2 = *(const f16x8*)(Zh + (size_t)c2 * OH + lane * 8);
      f16x8 z3 = *(const f16x8*)(Zh + (size_t)c3 * OH + lane * 8);
      const float* w0 = &wts[wid][e + 0][0];
      const float* w1 = &wts[wid][e + 1][0];
      const float* w2 = &wts[wid][e + 2][0];
      const float* w3 = &wts[wid][e + 3][0];
#pragma unroll
      for (int h = 0; h < 8; h++) {
        acc[h] = fmaf(w0[h], (float)z0[h], acc[h]);
        acc[h] = fmaf(w1[h], (float)z1[h], acc[h]);
        acc[h] = fmaf(w2[h], (float)z2[h], acc[h]);
        acc[h] = fmaf(w3[h], (float)z3[h], acc[h]);
      }
    }
    for (; e < cnt; e++) {
      int c = cls[wid][e];
      f16x8 z = *(const f16x8*)(Zh + (size_t)c * OH + lane * 8);
      const float* w = &wts[wid][e][0];
#pragma unroll
      for (int h = 0; h < 8; h++) acc[h] = fmaf(w[h], (float)z[h], acc[h]);
    }
  }

#pragma unroll
  for (int st = 1; st < 64; st <<= 1)
#pragma unroll
    for (int h = 0; h < 8; h++) den[h] += __shfl_xor(den[h], st);

  f32x4 o0, o1;
  o0[0] = acc[0] / den[0]; o0[1] = acc[1] / den[1];
  o0[2] = acc[2] / den[2]; o0[3] = acc[3] / den[3];
  o1[0] = acc[4] / den[4]; o1[1] = acc[5] / den[5];
  o1[2] = acc[6] / den[6]; o1[3] = acc[7] / den[7];
  __builtin_nontemporal_store(o0, (f32x4*)(out + (size_t)i * OH + lane * 8));
  __builtin_nontemporal_store(o1, (f32x4*)(out + (size_t)i * OH + lane * 8 + 4));
}

// ---------------------------------------------------------------------------
extern "C" void kernel_launch(void* const* d_in, const int* in_sizes, int n_in,
                              void* d_out, int out_size, void* d_ws, size_t ws_size,
                              hipStream_t stream) {
  const float* X    = (const float*)d_in[0];
  const float* W    = (const float*)d_in[1];
  const float* bias = (const float*)d_in[2];
  const float* a_l  = (const float*)d_in[3];
  const float* a_r  = (const float*)d_in[4];
  const int*   row  = (const int*)d_in[5];
  const int*   col  = (const int*)d_in[6];
  float* out = (float*)d_out;

  const int N = in_sizes[0] / IN_F;   // 50000
  const int E = in_sizes[5];          // 850000
  const int nWe = OH * IN_F;

  auto align_up = [](size_t v) { return (v + 255) & ~(size_t)255; };
  char* p = (char*)d_ws;
  half_t* Wh    = (half_t*)p; p += align_up((size_t)nWe * 2);
  half_t* Zh    = (half_t*)p; p += align_up((size_t)N * OH * 2);
  float* el     = (float*)p;  p += (size_t)N * NH * 4;        // el/er contiguous
  float* er     = (float*)p;  p += align_up((size_t)N * NH * 4);
  int*   deg    = (int*)p;    p += align_up((size_t)N * 4);
  int*   off    = (int*)p;    p += align_up((size_t)(N + 1) * 4);
  int*   cursor = (int*)p;    p += align_up((size_t)N * 4);
  int*   sums   = (int*)p;    p += align_up((size_t)64 * 4);
  int*   colS   = (int*)p;    p += align_up((size_t)E * 4);
  (void)ws_size; (void)n_in; (void)out_size;

  const int nb = (N + SCAN_B - 1) / SCAN_B;

  hipMemsetAsync(deg, 0, (size_t)N * 4, stream);
  hipMemsetAsync(el, 0, (size_t)2 * N * NH * 4, stream);

  hipLaunchKernelGGL(k_castW, dim3((nWe / 8 + 255) / 256), dim3(256), 0, stream,
                     W, Wh, nWe);

  // pipelined MFMA GEMM (reg-staged A depth-2, gload_lds B) + el/er epilogue
  const int nwg = ((N + 127) / 128) * 4;
  hipLaunchKernelGGL(k_gemm16_v5, dim3(nwg), dim3(256), 0, stream,
                     X, Wh, bias, a_l, a_r, Zh, el, er, N, nwg);

  // CSR build
  hipLaunchKernelGGL(k_hist, dim3((E + 255) / 256), dim3(256), 0, stream, row, deg, E);
  hipLaunchKernelGGL(k_scan1, dim3(nb), dim3(SCAN_B), 0, stream, deg, off, sums, N);
  hipLaunchKernelGGL(k_scan3, dim3(nb), dim3(SCAN_B), 0, stream,
                     off, cursor, sums, nb, N, E);
  hipLaunchKernelGGL(k_fill, dim3((E + 255) / 256), dim3(256), 0, stream,
                     row, col, cursor, colS, E);

  // fused softmax + aggregation
  hipLaunchKernelGGL(k_attagg, dim3((N + 3) / 4), dim3(256), 0, stream,
                     Zh, el, er, off, colS, out, N);
}

// Round 9
// 331.993 us; speedup vs baseline: 1.3275x; 1.0423x over previous
//
#include <hip/hip_runtime.h>
#include <hip/hip_fp16.h>

#define IN_F 512
#define OH   512   // OUT*H
#define NH   8     // heads

typedef _Float16 half_t;
typedef __attribute__((ext_vector_type(8))) _Float16 f16x8;
typedef __attribute__((ext_vector_type(4))) float    f32x4;

// ---------------------------------------------------------------------------
// fused: cast W f32->f16 (blocks [0,nbW)) + degree histogram (rest)
// ---------------------------------------------------------------------------
__global__ __launch_bounds__(256) void k_prep(const float* __restrict__ W,
                                              half_t* __restrict__ Wh, int nWe,
                                              const int* __restrict__ row,
                                              int* __restrict__ deg, int E,
                                              int nbW) {
  int b = blockIdx.x;
  if (b < nbW) {
    int i = (b * 256 + threadIdx.x) * 8;
    if (i >= nWe) return;
    float4 a = *(const float4*)(W + i);
    float4 c = *(const float4*)(W + i + 4);
    f16x8 h;
    h[0] = (half_t)a.x; h[1] = (half_t)a.y; h[2] = (half_t)a.z; h[3] = (half_t)a.w;
    h[4] = (half_t)c.x; h[5] = (half_t)c.y; h[6] = (half_t)c.z; h[7] = (half_t)c.w;
    *(f16x8*)(Wh + i) = h;
  } else {
    int e = (b - nbW) * 256 + threadIdx.x;
    if (e < E) atomicAdd(&deg[row[e]], 1);
  }
}

// ---------------------------------------------------------------------------
// MFMA f16 GEMM v6: B-panel-resident, barrier-free K-loop.
// Block = 512 thr (8 waves), output 256 rows x 128 cols.
// LDS: Bsm[128][516] f16 (~129 KB) = the ENTIRE K=512 panel of 128 W-cols,
// loaded once (one barrier).  K-loop (16 steps, fully unrolled, NO barriers):
// wave w owns rows n0+w*32..+32; per step: consume depth-2-prefetched f32 A
// regs (cvt->f16), 8 ds_read_b128 of B, 16 MFMA.  +516 pad => ~2-way LDS
// read aliasing (free).  XCD swizzle: 4 col-panels of a row-panel adjacent
// on one XCD -> X re-reads are L2-hits.
// Epilogue: Zh write + fused per-head el/er atomic partials.
// ---------------------------------------------------------------------------
__global__ __launch_bounds__(512) void k_gemm16_v6(const float* __restrict__ X,
                                                   const half_t* __restrict__ Wh,
                                                   const float* __restrict__ bias,
                                                   const float* __restrict__ al,
                                                   const float* __restrict__ ar,
                                                   half_t* __restrict__ Zh,
                                                   float* __restrict__ el,
                                                   float* __restrict__ er,
                                                   int N, int nwg) {
  __shared__ half_t Bsm[128][516];   // ~129 KB
  const int tid  = threadIdx.x;
  const int lane = tid & 63;
  const int wid  = tid >> 6;          // 0..7

  // bijective XCD swizzle (m204)
  int orig = blockIdx.x;
  int xcd = orig & 7;
  int q = nwg >> 3, r = nwg & 7;
  int start = (xcd < r) ? xcd * (q + 1) : r * (q + 1) + (xcd - r) * q;
  int work = start + (orig >> 3);
  const int n0 = (work >> 2) * 256;
  const int j0 = (work & 3) * 128;

  const int rl = lane & 15;
  const int hi16 = lane >> 4;

  // ---- B panel load: wave wid loads cols [wid*16, wid*16+16), 1 KB per col
  //      (lane reads 16B of the col's K-row -> fully coalesced).
#pragma unroll
  for (int c = 0; c < 16; c++) {
    int col = wid * 16 + c;
    f16x8 v = *(const f16x8*)(Wh + (size_t)(j0 + col) * IN_F + lane * 8);
    *(f16x8*)&Bsm[col][lane * 8] = v;
  }
  __syncthreads();

  // ---- A row pointers (2 m-tiles of 16 rows per wave)
  const float* aSrc[2];
#pragma unroll
  for (int m = 0; m < 2; m++) {
    int rr = n0 + wid * 32 + m * 16 + rl;
    if (rr >= N) rr = N - 1;
    aSrc[m] = X + (size_t)rr * IN_F + hi16 * 8;
  }

  f32x4 acc[2][8] = {};
  f32x4 ap[2][2][2];   // [step&1][m][lo/hi] -- static after full unroll

  // prologue: preload A(0), A(1)
#pragma unroll
  for (int m = 0; m < 2; m++) {
    ap[0][m][0] = *(const f32x4*)(aSrc[m] + 0);
    ap[0][m][1] = *(const f32x4*)(aSrc[m] + 4);
    ap[1][m][0] = *(const f32x4*)(aSrc[m] + 32);
    ap[1][m][1] = *(const f32x4*)(aSrc[m] + 36);
  }

#pragma unroll
  for (int k = 0; k < 16; k++) {
    // consume A(k)
    f16x8 af[2];
#pragma unroll
    for (int m = 0; m < 2; m++) {
      f32x4 lo = ap[k & 1][m][0];
      f32x4 hi = ap[k & 1][m][1];
      f16x8 a;
#pragma unroll
      for (int u = 0; u < 4; u++) { a[u] = (half_t)lo[u]; a[u + 4] = (half_t)hi[u]; }
      af[m] = a;
    }
    // prefetch A(k+2) into the slot just freed
    if (k + 2 < 16) {
#pragma unroll
      for (int m = 0; m < 2; m++) {
        ap[k & 1][m][0] = *(const f32x4*)(aSrc[m] + (k + 2) * 32);
        ap[k & 1][m][1] = *(const f32x4*)(aSrc[m] + (k + 2) * 32 + 4);
      }
    }
    // B reads + MFMA (no barriers -- Bsm is read-only now)
#pragma unroll
    for (int n = 0; n < 8; n++) {
      f16x8 bf = *(const f16x8*)&Bsm[n * 16 + rl][k * 32 + hi16 * 8];
      acc[0][n] = __builtin_amdgcn_mfma_f32_16x16x32_f16(af[0], bf, acc[0][n], 0, 0, 0);
      acc[1][n] = __builtin_amdgcn_mfma_f32_16x16x32_f16(af[1], bf, acc[1][n], 0, 0, 0);
    }
  }

  // ---- epilogue: Zh write + per-head el/er partials ----
  // C/D layout: col=lane&15, row=(lane>>4)*4+q.  Lane's head h = rl & 7.
  float bv[8], av[8], rv[8];
#pragma unroll
  for (int n = 0; n < 8; n++) {
    int j = j0 + n * 16 + rl;
    bv[n] = bias[j]; av[n] = al[j]; rv[n] = ar[j];
  }

  float partl[2][4], partr[2][4];
#pragma unroll
  for (int m = 0; m < 2; m++)
#pragma unroll
    for (int qq = 0; qq < 4; qq++) { partl[m][qq] = 0.f; partr[m][qq] = 0.f; }

#pragma unroll
  for (int n = 0; n < 8; n++) {
    int j = j0 + n * 16 + rl;
#pragma unroll
    for (int m = 0; m < 2; m++) {
      int rbase = n0 + wid * 32 + m * 16 + hi16 * 4;
#pragma unroll
      for (int qq = 0; qq < 4; qq++) {
        float v = acc[m][n][qq] + bv[n];
        int nrow = rbase + qq;
        if (nrow < N) Zh[(size_t)nrow * OH + j] = (half_t)v;
        partl[m][qq] = fmaf(v, av[n], partl[m][qq]);
        partr[m][qq] = fmaf(v, rv[n], partr[m][qq]);
      }
    }
  }
  const int h = rl & 7;
#pragma unroll
  for (int m = 0; m < 2; m++) {
#pragma unroll
    for (int qq = 0; qq < 4; qq++) {
      float pl = partl[m][qq], pr = partr[m][qq];
      pl += __shfl_xor(pl, 8);    // fold rl and rl+8 (same head)
      pr += __shfl_xor(pr, 8);
      if (rl < 8) {
        int nrow = n0 + wid * 32 + m * 16 + hi16 * 4 + qq;
        if (nrow < N) {
          atomicAdd(&el[(size_t)nrow * NH + h], pl);
          atomicAdd(&er[(size_t)nrow * NH + h], pr);
        }
      }
    }
  }
}

// ---------------------------------------------------------------------------
// CSR build
// ---------------------------------------------------------------------------
#define SCAN_B 1024
__global__ __launch_bounds__(SCAN_B) void k_scan1(const int* __restrict__ deg,
                                                  int* __restrict__ off,
                                                  int* __restrict__ sums, int N) {
  __shared__ int s[SCAN_B];
  int tid = threadIdx.x;
  int g = blockIdx.x * SCAN_B + tid;
  int v = (g < N) ? deg[g] : 0;
  s[tid] = v;
  __syncthreads();
  for (int o = 1; o < SCAN_B; o <<= 1) {
    int t = (tid >= o) ? s[tid - o] : 0;
    __syncthreads();
    s[tid] += t;
    __syncthreads();
  }
  if (g < N) off[g] = s[tid] - v;
  if (tid == SCAN_B - 1) sums[blockIdx.x] = s[tid];
}

__global__ __launch_bounds__(SCAN_B) void k_scan3(int* __restrict__ off,
                                                  int* __restrict__ cursor,
                                                  const int* __restrict__ sums,
                                                  int nb, int N, int E) {
  __shared__ int sboff;
  int tid = threadIdx.x;
  if (tid < 64) {
    int v = (tid < nb && tid < (int)blockIdx.x) ? sums[tid] : 0;
#pragma unroll
    for (int s = 1; s < 64; s <<= 1) v += __shfl_xor(v, s);
    if (tid == 0) sboff = v;
  }
  __syncthreads();
  int g = blockIdx.x * SCAN_B + tid;
  if (g < N) {
    int v = off[g] + sboff;
    off[g] = v;
    cursor[g] = v;
  }
  if (g == 0) off[N] = E;
}

__global__ void k_fill(const int* __restrict__ row, const int* __restrict__ col,
                       int* __restrict__ cursor, int* __restrict__ colS, int E) {
  int e = blockIdx.x * blockDim.x + threadIdx.x;
  if (e < E) {
    int r = row[e];
    int p = atomicAdd(&cursor[r], 1);
    colS[p] = col[e];
  }
}

// ---------------------------------------------------------------------------
// Fused edge-softmax + aggregation (NT store for out, NT load for colS)
// ---------------------------------------------------------------------------
__global__ __launch_bounds__(256) void k_attagg(const half_t* __restrict__ Zh,
                                                const float* __restrict__ el,
                                                const float* __restrict__ er,
                                                const int* __restrict__ off,
                                                const int* __restrict__ colS,
                                                float* __restrict__ out, int N) {
  __shared__ float wts[4][64][NH];   // 8 KB
  __shared__ int   cls[4][64];       // 1 KB
  int wid = threadIdx.x >> 6, lane = threadIdx.x & 63;
  int i = blockIdx.x * 4 + wid;
  if (i >= N) return;
  int s = off[i], t = off[i + 1];
  int deg = t - s;

  float eli[8];
  {
    const float4* e4 = (const float4*)(el + (size_t)i * NH);
    float4 a = e4[0], b = e4[1];
    eli[0] = a.x; eli[1] = a.y; eli[2] = a.z; eli[3] = a.w;
    eli[4] = b.x; eli[5] = b.y; eli[6] = b.z; eli[7] = b.w;
  }

  float m[8], ehs[8];
  int csave = 0;
#pragma unroll
  for (int h = 0; h < 8; h++) m[h] = -1e30f;
  for (int p = s + lane; p < t; p += 64) {
    int c = __builtin_nontemporal_load(&colS[p]);
    csave = c;
    const float4* e4 = (const float4*)(er + (size_t)c * NH);
    float4 ea = e4[0], eb = e4[1];
    float ev[8] = {ea.x, ea.y, ea.z, ea.w, eb.x, eb.y, eb.z, eb.w};
#pragma unroll
    for (int h = 0; h < 8; h++) {
      float eh = eli[h] + ev[h];
      eh = (eh > 0.f) ? eh : 0.01f * eh;
      ehs[h] = eh;
      m[h] = fmaxf(m[h], eh);
    }
  }
#pragma unroll
  for (int st = 1; st < 64; st <<= 1)
#pragma unroll
    for (int h = 0; h < 8; h++) m[h] = fmaxf(m[h], __shfl_xor(m[h], st));

  float acc[8], den[8];
#pragma unroll
  for (int h = 0; h < 8; h++) { acc[h] = 0.f; den[h] = 0.f; }

  for (int base = s; base < t; base += 64) {
    int p = base + lane;
    if (p < t) {
      int c;
      float eh[8];
      if (deg <= 64) {
        c = csave;
#pragma unroll
        for (int h = 0; h < 8; h++) eh[h] = ehs[h];
      } else {
        c = __builtin_nontemporal_load(&colS[p]);
        const float4* e4 = (const float4*)(er + (size_t)c * NH);
        float4 ea = e4[0], eb = e4[1];
        float ev[8] = {ea.x, ea.y, ea.z, ea.w, eb.x, eb.y, eb.z, eb.w};
#pragma unroll
        for (int h = 0; h < 8; h++) {
          float e2 = eli[h] + ev[h];
          eh[h] = (e2 > 0.f) ? e2 : 0.01f * e2;
        }
      }
      cls[wid][lane] = c;
#pragma unroll
      for (int h = 0; h < 8; h++) {
        float pr = __expf(eh[h] - m[h]);
        den[h] += pr;
        wts[wid][lane][h] = pr;
      }
    }
    int cnt = t - base; if (cnt > 64) cnt = 64;

    int e = 0;
    for (; e + 4 <= cnt; e += 4) {
      int c0 = cls[wid][e + 0], c1 = cls[wid][e + 1];
      int c2 = cls[wid][e + 2], c3 = cls[wid][e + 3];
      f16x8 z0 = *(const f16x8*)(Zh + (size_t)c0 * OH + lane * 8);
      f16x8 z1 = *(const f16x8*)(Zh + (size_t)c1 * OH + lane * 8);
      f16x8 z2 = *(const f16x8*)(Zh + (size_t)c2 * OH + lane * 8);
      f16x8 z3 = *(const f16x8*)(Zh + (size_t)c3 * OH + lane * 8);
      const float* w0 = &wts[wid][e + 0][0];
      const float* w1 = &wts[wid][e + 1][0];
      const float* w2 = &wts[wid][e + 2][0];
      const float* w3 = &wts[wid][e + 3][0];
#pragma unroll
      for (int h = 0; h < 8; h++) {
        acc[h] = fmaf(w0[h], (float)z0[h], acc[h]);
        acc[h] = fmaf(w1[h], (float)z1[h], acc[h]);
        acc[h] = fmaf(w2[h], (float)z2[h], acc[h]);
        acc[h] = fmaf(w3[h], (float)z3[h], acc[h]);
      }
    }
    for (; e < cnt; e++) {
      int c = cls[wid][e];
      f16x8 z = *(const f16x8*)(Zh + (size_t)c * OH + lane * 8);
      const float* w = &wts[wid][e][0];
#pragma unroll
      for (int h = 0; h < 8; h++) acc[h] = fmaf(w[h], (float)z[h], acc[h]);
    }
  }

#pragma unroll
  for (int st = 1; st < 64; st <<= 1)
#pragma unroll
    for (int h = 0; h < 8; h++) den[h] += __shfl_xor(den[h], st);

  f32x4 o0, o1;
  o0[0] = acc[0] / den[0]; o0[1] = acc[1] / den[1];
  o0[2] = acc[2] / den[2]; o0[3] = acc[3] / den[3];
  o1[0] = acc[4] / den[4]; o1[1] = acc[5] / den[5];
  o1[2] = acc[6] / den[6]; o1[3] = acc[7] / den[7];
  __builtin_nontemporal_store(o0, (f32x4*)(out + (size_t)i * OH + lane * 8));
  __builtin_nontemporal_store(o1, (f32x4*)(out + (size_t)i * OH + lane * 8 + 4));
}

// ---------------------------------------------------------------------------
extern "C" void kernel_launch(void* const* d_in, const int* in_sizes, int n_in,
                              void* d_out, int out_size, void* d_ws, size_t ws_size,
                              hipStream_t stream) {
  const float* X    = (const float*)d_in[0];
  const float* W    = (const float*)d_in[1];
  const float* bias = (const float*)d_in[2];
  const float* a_l  = (const float*)d_in[3];
  const float* a_r  = (const float*)d_in[4];
  const int*   row  = (const int*)d_in[5];
  const int*   col  = (const int*)d_in[6];
  float* out = (float*)d_out;

  const int N = in_sizes[0] / IN_F;   // 50000
  const int E = in_sizes[5];          // 850000
  const int nWe = OH * IN_F;

  auto align_up = [](size_t v) { return (v + 255) & ~(size_t)255; };
  char* p = (char*)d_ws;
  half_t* Wh    = (half_t*)p; p += align_up((size_t)nWe * 2);
  half_t* Zh    = (half_t*)p; p += align_up((size_t)N * OH * 2);
  float* el     = (float*)p;  p += (size_t)N * NH * 4;        // el/er contiguous
  float* er     = (float*)p;  p += align_up((size_t)N * NH * 4);
  int*   deg    = (int*)p;    p += align_up((size_t)N * 4);
  int*   off    = (int*)p;    p += align_up((size_t)(N + 1) * 4);
  int*   cursor = (int*)p;    p += align_up((size_t)N * 4);
  int*   sums   = (int*)p;    p += align_up((size_t)64 * 4);
  int*   colS   = (int*)p;    p += align_up((size_t)E * 4);
  (void)ws_size; (void)n_in; (void)out_size;

  const int nb = (N + SCAN_B - 1) / SCAN_B;

  hipMemsetAsync(deg, 0, (size_t)N * 4, stream);
  hipMemsetAsync(el, 0, (size_t)2 * N * NH * 4, stream);

  // fused castW + degree histogram
  const int nbW = (nWe / 8 + 255) / 256;
  const int nbH = (E + 255) / 256;
  hipLaunchKernelGGL(k_prep, dim3(nbW + nbH), dim3(256), 0, stream,
                     W, Wh, nWe, row, deg, E, nbW);

  // B-resident barrier-free MFMA GEMM + el/er epilogue
  const int nwg = ((N + 255) / 256) * 4;
  hipLaunchKernelGGL(k_gemm16_v6, dim3(nwg), dim3(512), 0, stream,
                     X, Wh, bias, a_l, a_r, Zh, el, er, N, nwg);

  // CSR build
  hipLaunchKernelGGL(k_scan1, dim3(nb), dim3(SCAN_B), 0, stream, deg, off, sums, N);
  hipLaunchKernelGGL(k_scan3, dim3(nb), dim3(SCAN_B), 0, stream,
                     off, cursor, sums, nb, N, E);
  hipLaunchKernelGGL(k_fill, dim3((E + 255) / 256), dim3(256), 0, stream,
                     row, col, cursor, colS, E);

  // fused softmax + aggregation
  hipLaunchKernelGGL(k_attagg, dim3((N + 3) / 4), dim3(256), 0, stream,
                     Zh, el, er, off, colS, out, N);
}

// Round 10
// 310.607 us; speedup vs baseline: 1.4189x; 1.0689x over previous
//
#include <hip/hip_runtime.h>
#include <hip/hip_fp16.h>

#define IN_F 512
#define OH   512   // OUT*H
#define NH   8     // heads

typedef _Float16 half_t;
typedef __attribute__((ext_vector_type(8))) _Float16 f16x8;
typedef __attribute__((ext_vector_type(4))) float    f32x4;

#define GLOBAL_AS const __attribute__((address_space(1))) void
#define LDS_AS    __attribute__((address_space(3))) void

__device__ static inline void gload_lds16(const void* g, void* l) {
  __builtin_amdgcn_global_load_lds((GLOBAL_AS*)g, (LDS_AS*)l, 16, 0, 0);
}

// ---------------------------------------------------------------------------
// fused: cast W f32->f16 (blocks [0,nbW)) + degree histogram (rest)
// ---------------------------------------------------------------------------
__global__ __launch_bounds__(256) void k_prep(const float* __restrict__ W,
                                              half_t* __restrict__ Wh, int nWe,
                                              const int* __restrict__ row,
                                              int* __restrict__ deg, int E,
                                              int nbW) {
  int b = blockIdx.x;
  if (b < nbW) {
    int i = (b * 256 + threadIdx.x) * 8;
    if (i >= nWe) return;
    float4 a = *(const float4*)(W + i);
    float4 c = *(const float4*)(W + i + 4);
    f16x8 h;
    h[0] = (half_t)a.x; h[1] = (half_t)a.y; h[2] = (half_t)a.z; h[3] = (half_t)a.w;
    h[4] = (half_t)c.x; h[5] = (half_t)c.y; h[6] = (half_t)c.z; h[7] = (half_t)c.w;
    *(f16x8*)(Wh + i) = h;
  } else {
    int e = (b - nbW) * 256 + threadIdx.x;
    if (e < E) atomicAdd(&deg[row[e]], 1);
  }
}

// ---------------------------------------------------------------------------
// MFMA f16 GEMM v7: full-width blocks -> X read ONCE per row-panel.
// Block = 512 thr (8 waves, wr=wid>>2 in 0..1, wc=wid&3 in 0..3).
// Output 128 rows x 512 cols; wave tile 64x128 (4m x 8n of 16x16x32).
// LDS (96KB): As[2][128*32]f32 (2x16KB), Bs[2][512*32]f16 (2x32KB), linear
// (global_load_lds) with granule-XOR swizzle applied to the GLOBAL source +
// the ds_read side (rule #21):  A: sg^(row&7) -> 2-way banks;
// B: g^((jrow>>1)&3) -> 2-way banks (enumerated).
// Pipeline: double-buffer, issue STAGE(k+1) then s_waitcnt vmcnt(6) (stage k
// complete, k+1 in flight), raw s_barrier; compute; barrier.  (v5's verified
// sync pattern.)  Epilogue: Zh store + fused per-head el/er atomic partials.
// ---------------------------------------------------------------------------
__global__ __launch_bounds__(512, 2) void k_gemm16_v7(const float* __restrict__ X,
                                                      const half_t* __restrict__ Wh,
                                                      const float* __restrict__ bias,
                                                      const float* __restrict__ al,
                                                      const float* __restrict__ ar,
                                                      half_t* __restrict__ Zh,
                                                      float* __restrict__ el,
                                                      float* __restrict__ er,
                                                      int N, int nwg) {
  __shared__ float  As[2][128 * 32];   // 2 x 16 KB, linear
  __shared__ half_t Bs[2][512 * 32];   // 2 x 32 KB, linear
  const int tid  = threadIdx.x;
  const int lane = tid & 63;
  const int wid  = tid >> 6;           // 0..7
  const int wr = wid >> 2, wc = wid & 3;

  // bijective XCD swizzle (m204) -- for Zh/W L2 locality
  int orig = blockIdx.x;
  int xcd = orig & 7;
  int q = nwg >> 3, r = nwg & 7;
  int start = (xcd < r) ? xcd * (q + 1) : r * (q + 1) + (xcd - r) * q;
  int work = start + (orig >> 3);
  const int n0 = work * 128;

  const int rl = lane & 15;
  const int hi16 = lane >> 4;

  // ---- staging maps (kt-invariant) ----
  // A: 16KB/stage = 2 calls x (8 waves x 1KB).  off = c*8192 + wid*1024 + lane*16
  int a_row[2], a_goff[2];
#pragma unroll
  for (int c = 0; c < 2; c++) {
    int off = c * 8192 + wid * 1024 + lane * 16;
    int rrow = off >> 7;                 // 0..127 (128B per f32 row)
    int sg = (off >> 4) & 7;             // LDS granule in row
    a_row[c]  = rrow;
    a_goff[c] = (sg ^ (rrow & 7)) << 2;  // source f32 offset in row
  }
  // B: 32KB/stage = 4 calls.  off = c*8192 + wid*1024 + lane*16
  int b_row[4], b_goff[4];
#pragma unroll
  for (int c = 0; c < 4; c++) {
    int off = c * 8192 + wid * 1024 + lane * 16;
    int jr = off >> 6;                   // 0..511 (64B per f16 row)
    int g  = (off >> 4) & 3;
    b_row[c]  = jr;
    b_goff[c] = (g ^ ((jr >> 1) & 3)) << 3;  // source half offset in row
  }

#define STAGE(BUF, KT)                                                          \
  do {                                                                          \
    _Pragma("unroll")                                                           \
    for (int c = 0; c < 2; c++) {                                               \
      int an = n0 + a_row[c]; if (an >= N) an = N - 1;                          \
      const float* g = X + (size_t)an * IN_F + (KT) + a_goff[c];                \
      gload_lds16(g, (char*)&As[BUF][0] + c * 8192 + wid * 1024);               \
    }                                                                           \
    _Pragma("unroll")                                                           \
    for (int c = 0; c < 4; c++) {                                               \
      const half_t* g = Wh + (size_t)b_row[c] * IN_F + (KT) + b_goff[c];        \
      gload_lds16(g, (char*)&Bs[BUF][0] + c * 8192 + wid * 1024);               \
    }                                                                           \
  } while (0)

  f32x4 acc[4][8] = {};

  STAGE(0, 0);

#pragma unroll
  for (int ki = 0; ki < 16; ki++) {
    const int cur = ki & 1;
    if (ki < 15) {
      STAGE(cur ^ 1, (ki + 1) * 32);
      asm volatile("s_waitcnt vmcnt(6)" ::: "memory");   // stage ki complete
    } else {
      asm volatile("s_waitcnt vmcnt(0)" ::: "memory");
    }
    __builtin_amdgcn_sched_barrier(0);
    __builtin_amdgcn_s_barrier();

    // ---- fragments (swizzled ds_read) ----
    f16x8 af[4], bf[8];
#pragma unroll
    for (int m = 0; m < 4; m++) {
      int rr = wr * 64 + m * 16 + rl;
      int r7 = rr & 7;
      const char* base = (const char*)&As[cur][0] + rr * 128;
      f32x4 lo = *(const f32x4*)(base + (((hi16 * 2) ^ r7) << 4));
      f32x4 hi = *(const f32x4*)(base + (((hi16 * 2 + 1) ^ r7) << 4));
      f16x8 a;
#pragma unroll
      for (int u = 0; u < 4; u++) { a[u] = (half_t)lo[u]; a[u + 4] = (half_t)hi[u]; }
      af[m] = a;
    }
#pragma unroll
    for (int n = 0; n < 8; n++) {
      int jr = wc * 128 + n * 16 + rl;
      bf[n] = *(const f16x8*)((const char*)&Bs[cur][0] + jr * 64 +
                              ((hi16 ^ ((jr >> 1) & 3)) << 4));
    }
#pragma unroll
    for (int m = 0; m < 4; m++)
#pragma unroll
      for (int n = 0; n < 8; n++)
        acc[m][n] = __builtin_amdgcn_mfma_f32_16x16x32_f16(af[m], bf[n], acc[m][n], 0, 0, 0);

    __builtin_amdgcn_s_barrier();   // all reads of buf[cur] done before restage
  }
#undef STAGE

  // ---- epilogue: Zh write + per-head el/er partials ----
  // C/D layout: col=lane&15, row=(lane>>4)*4+q.  Lane's head h = rl & 7.
  float bv[8], av[8], rv[8];
#pragma unroll
  for (int n = 0; n < 8; n++) {
    int j = wc * 128 + n * 16 + rl;
    bv[n] = bias[j]; av[n] = al[j]; rv[n] = ar[j];
  }

  float partl[4][4], partr[4][4];
#pragma unroll
  for (int m = 0; m < 4; m++)
#pragma unroll
    for (int qq = 0; qq < 4; qq++) { partl[m][qq] = 0.f; partr[m][qq] = 0.f; }

#pragma unroll
  for (int n = 0; n < 8; n++) {
    int j = wc * 128 + n * 16 + rl;
#pragma unroll
    for (int m = 0; m < 4; m++) {
      int rbase = n0 + wr * 64 + m * 16 + hi16 * 4;
#pragma unroll
      for (int qq = 0; qq < 4; qq++) {
        float v = acc[m][n][qq] + bv[n];
        int nrow = rbase + qq;
        if (nrow < N) Zh[(size_t)nrow * OH + j] = (half_t)v;
        partl[m][qq] = fmaf(v, av[n], partl[m][qq]);
        partr[m][qq] = fmaf(v, rv[n], partr[m][qq]);
      }
    }
  }
  const int h = rl & 7;
#pragma unroll
  for (int m = 0; m < 4; m++) {
#pragma unroll
    for (int qq = 0; qq < 4; qq++) {
      float pl = partl[m][qq], pr = partr[m][qq];
      pl += __shfl_xor(pl, 8);    // fold rl and rl+8 (same head)
      pr += __shfl_xor(pr, 8);
      if (rl < 8) {
        int nrow = n0 + wr * 64 + m * 16 + hi16 * 4 + qq;
        if (nrow < N) {
          atomicAdd(&el[(size_t)nrow * NH + h], pl);
          atomicAdd(&er[(size_t)nrow * NH + h], pr);
        }
      }
    }
  }
}

// ---------------------------------------------------------------------------
// CSR build
// ---------------------------------------------------------------------------
#define SCAN_B 1024
__global__ __launch_bounds__(SCAN_B) void k_scan1(const int* __restrict__ deg,
                                                  int* __restrict__ off,
                                                  int* __restrict__ sums, int N) {
  __shared__ int s[SCAN_B];
  int tid = threadIdx.x;
  int g = blockIdx.x * SCAN_B + tid;
  int v = (g < N) ? deg[g] : 0;
  s[tid] = v;
  __syncthreads();
  for (int o = 1; o < SCAN_B; o <<= 1) {
    int t = (tid >= o) ? s[tid - o] : 0;
    __syncthreads();
    s[tid] += t;
    __syncthreads();
  }
  if (g < N) off[g] = s[tid] - v;
  if (tid == SCAN_B - 1) sums[blockIdx.x] = s[tid];
}

__global__ __launch_bounds__(SCAN_B) void k_scan3(int* __restrict__ off,
                                                  int* __restrict__ cursor,
                                                  const int* __restrict__ sums,
                                                  int nb, int N, int E) {
  __shared__ int sboff;
  int tid = threadIdx.x;
  if (tid < 64) {
    int v = (tid < nb && tid < (int)blockIdx.x) ? sums[tid] : 0;
#pragma unroll
    for (int s = 1; s < 64; s <<= 1) v += __shfl_xor(v, s);
    if (tid == 0) sboff = v;
  }
  __syncthreads();
  int g = blockIdx.x * SCAN_B + tid;
  if (g < N) {
    int v = off[g] + sboff;
    off[g] = v;
    cursor[g] = v;
  }
  if (g == 0) off[N] = E;
}

__global__ void k_fill(const int* __restrict__ row, const int* __restrict__ col,
                       int* __restrict__ cursor, int* __restrict__ colS, int E) {
  int e = blockIdx.x * blockDim.x + threadIdx.x;
  if (e < E) {
    int r = row[e];
    int p = atomicAdd(&cursor[r], 1);
    colS[p] = col[e];
  }
}

// ---------------------------------------------------------------------------
// Fused edge-softmax + aggregation (NT store for out, NT load for colS)
// ---------------------------------------------------------------------------
__global__ __launch_bounds__(256) void k_attagg(const half_t* __restrict__ Zh,
                                                const float* __restrict__ el,
                                                const float* __restrict__ er,
                                                const int* __restrict__ off,
                                                const int* __restrict__ colS,
                                                float* __restrict__ out, int N) {
  __shared__ float wts[4][64][NH];   // 8 KB
  __shared__ int   cls[4][64];       // 1 KB
  int wid = threadIdx.x >> 6, lane = threadIdx.x & 63;
  int i = blockIdx.x * 4 + wid;
  if (i >= N) return;
  int s = off[i], t = off[i + 1];
  int deg = t - s;

  float eli[8];
  {
    const float4* e4 = (const float4*)(el + (size_t)i * NH);
    float4 a = e4[0], b = e4[1];
    eli[0] = a.x; eli[1] = a.y; eli[2] = a.z; eli[3] = a.w;
    eli[4] = b.x; eli[5] = b.y; eli[6] = b.z; eli[7] = b.w;
  }

  float m[8], ehs[8];
  int csave = 0;
#pragma unroll
  for (int h = 0; h < 8; h++) m[h] = -1e30f;
  for (int p = s + lane; p < t; p += 64) {
    int c = __builtin_nontemporal_load(&colS[p]);
    csave = c;
    const float4* e4 = (const float4*)(er + (size_t)c * NH);
    float4 ea = e4[0], eb = e4[1];
    float ev[8] = {ea.x, ea.y, ea.z, ea.w, eb.x, eb.y, eb.z, eb.w};
#pragma unroll
    for (int h = 0; h < 8; h++) {
      float eh = eli[h] + ev[h];
      eh = (eh > 0.f) ? eh : 0.01f * eh;
      ehs[h] = eh;
      m[h] = fmaxf(m[h], eh);
    }
  }
#pragma unroll
  for (int st = 1; st < 64; st <<= 1)
#pragma unroll
    for (int h = 0; h < 8; h++) m[h] = fmaxf(m[h], __shfl_xor(m[h], st));

  float acc[8], den[8];
#pragma unroll
  for (int h = 0; h < 8; h++) { acc[h] = 0.f; den[h] = 0.f; }

  for (int base = s; base < t; base += 64) {
    int p = base + lane;
    if (p < t) {
      int c;
      float eh[8];
      if (deg <= 64) {
        c = csave;
#pragma unroll
        for (int h = 0; h < 8; h++) eh[h] = ehs[h];
      } else {
        c = __builtin_nontemporal_load(&colS[p]);
        const float4* e4 = (const float4*)(er + (size_t)c * NH);
        float4 ea = e4[0], eb = e4[1];
        float ev[8] = {ea.x, ea.y, ea.z, ea.w, eb.x, eb.y, eb.z, eb.w};
#pragma unroll
        for (int h = 0; h < 8; h++) {
          float e2 = eli[h] + ev[h];
          eh[h] = (e2 > 0.f) ? e2 : 0.01f * e2;
        }
      }
      cls[wid][lane] = c;
#pragma unroll
      for (int h = 0; h < 8; h++) {
        float pr = __expf(eh[h] - m[h]);
        den[h] += pr;
        wts[wid][lane][h] = pr;
      }
    }
    int cnt = t - base; if (cnt > 64) cnt = 64;

    int e = 0;
    for (; e + 4 <= cnt; e += 4) {
      int c0 = cls[wid][e + 0], c1 = cls[wid][e + 1];
      int c2 = cls[wid][e + 2], c3 = cls[wid][e + 3];
      f16x8 z0 = *(const f16x8*)(Zh + (size_t)c0 * OH + lane * 8);
      f16x8 z1 = *(const f16x8*)(Zh + (size_t)c1 * OH + lane * 8);
      f16x8 z2 = *(const f16x8*)(Zh + (size_t)c2 * OH + lane * 8);
      f16x8 z3 = *(const f16x8*)(Zh + (size_t)c3 * OH + lane * 8);
      const float* w0 = &wts[wid][e + 0][0];
      const float* w1 = &wts[wid][e + 1][0];
      const float* w2 = &wts[wid][e + 2][0];
      const float* w3 = &wts[wid][e + 3][0];
#pragma unroll
      for (int h = 0; h < 8; h++) {
        acc[h] = fmaf(w0[h], (float)z0[h], acc[h]);
        acc[h] = fmaf(w1[h], (float)z1[h], acc[h]);
        acc[h] = fmaf(w2[h], (float)z2[h], acc[h]);
        acc[h] = fmaf(w3[h], (float)z3[h], acc[h]);
      }
    }
    for (; e < cnt; e++) {
      int c = cls[wid][e];
      f16x8 z = *(const f16x8*)(Zh + (size_t)c * OH + lane * 8);
      const float* w = &wts[wid][e][0];
#pragma unroll
      for (int h = 0; h < 8; h++) acc[h] = fmaf(w[h], (float)z[h], acc[h]);
    }
  }

#pragma unroll
  for (int st = 1; st < 64; st <<= 1)
#pragma unroll
    for (int h = 0; h < 8; h++) den[h] += __shfl_xor(den[h], st);

  f32x4 o0, o1;
  o0[0] = acc[0] / den[0]; o0[1] = acc[1] / den[1];
  o0[2] = acc[2] / den[2]; o0[3] = acc[3] / den[3];
  o1[0] = acc[4] / den[4]; o1[1] = acc[5] / den[5];
  o1[2] = acc[6] / den[6]; o1[3] = acc[7] / den[7];
  __builtin_nontemporal_store(o0, (f32x4*)(out + (size_t)i * OH + lane * 8));
  __builtin_nontemporal_store(o1, (f32x4*)(out + (size_t)i * OH + lane * 8 + 4));
}

// ---------------------------------------------------------------------------
extern "C" void kernel_launch(void* const* d_in, const int* in_sizes, int n_in,
                              void* d_out, int out_size, void* d_ws, size_t ws_size,
                              hipStream_t stream) {
  const float* X    = (const float*)d_in[0];
  const float* W    = (const float*)d_in[1];
  const float* bias = (const float*)d_in[2];
  const float* a_l  = (const float*)d_in[3];
  const float* a_r  = (const float*)d_in[4];
  const int*   row  = (const int*)d_in[5];
  const int*   col  = (const int*)d_in[6];
  float* out = (float*)d_out;

  const int N = in_sizes[0] / IN_F;   // 50000
  const int E = in_sizes[5];          // 850000
  const int nWe = OH * IN_F;

  auto align_up = [](size_t v) { return (v + 255) & ~(size_t)255; };
  char* p = (char*)d_ws;
  half_t* Wh    = (half_t*)p; p += align_up((size_t)nWe * 2);
  half_t* Zh    = (half_t*)p; p += align_up((size_t)N * OH * 2);
  float* el     = (float*)p;  p += (size_t)N * NH * 4;        // el/er contiguous
  float* er     = (float*)p;  p += align_up((size_t)N * NH * 4);
  int*   deg    = (int*)p;    p += align_up((size_t)N * 4);
  int*   off    = (int*)p;    p += align_up((size_t)(N + 1) * 4);
  int*   cursor = (int*)p;    p += align_up((size_t)N * 4);
  int*   sums   = (int*)p;    p += align_up((size_t)64 * 4);
  int*   colS   = (int*)p;    p += align_up((size_t)E * 4);
  (void)ws_size; (void)n_in; (void)out_size;

  const int nb = (N + SCAN_B - 1) / SCAN_B;

  hipMemsetAsync(deg, 0, (size_t)N * 4, stream);
  hipMemsetAsync(el, 0, (size_t)2 * N * NH * 4, stream);

  // fused castW + degree histogram
  const int nbW = (nWe / 8 + 255) / 256;
  const int nbH = (E + 255) / 256;
  hipLaunchKernelGGL(k_prep, dim3(nbW + nbH), dim3(256), 0, stream,
                     W, Wh, nWe, row, deg, E, nbW);

  // full-width MFMA GEMM (X read once per panel) + el/er epilogue
  const int nwg = (N + 127) / 128;
  hipLaunchKernelGGL(k_gemm16_v7, dim3(nwg), dim3(512), 0, stream,
                     X, Wh, bias, a_l, a_r, Zh, el, er, N, nwg);

  // CSR build
  hipLaunchKernelGGL(k_scan1, dim3(nb), dim3(SCAN_B), 0, stream, deg, off, sums, N);
  hipLaunchKernelGGL(k_scan3, dim3(nb), dim3(SCAN_B), 0, stream,
                     off, cursor, sums, nb, N, E);
  hipLaunchKernelGGL(k_fill, dim3((E + 255) / 256), dim3(256), 0, stream,
                     row, col, cursor, colS, E);

  // fused softmax + aggregation
  hipLaunchKernelGGL(k_attagg, dim3((N + 3) / 4), dim3(256), 0, stream,
                     Zh, el, er, off, colS, out, N);
}

// Round 11
// 306.841 us; speedup vs baseline: 1.4363x; 1.0123x over previous
//
#include <hip/hip_runtime.h>
#include <hip/hip_fp16.h>

#define IN_F 512
#define OH   512   // OUT*H
#define NH   8     // heads

typedef _Float16 half_t;
typedef __attribute__((ext_vector_type(8))) _Float16 f16x8;
typedef __attribute__((ext_vector_type(4))) float    f32x4;

#define GLOBAL_AS const __attribute__((address_space(1))) void
#define LDS_AS    __attribute__((address_space(3))) void

__device__ static inline void gload_lds16(const void* g, void* l) {
  __builtin_amdgcn_global_load_lds((GLOBAL_AS*)g, (LDS_AS*)l, 16, 0, 0);
}

// ---------------------------------------------------------------------------
// fused: cast W f32->f16 (blocks [0,nbW)) + degree histogram (rest)
// ---------------------------------------------------------------------------
__global__ __launch_bounds__(256) void k_prep(const float* __restrict__ W,
                                              half_t* __restrict__ Wh, int nWe,
                                              const int* __restrict__ row,
                                              int* __restrict__ deg, int E,
                                              int nbW) {
  int b = blockIdx.x;
  if (b < nbW) {
    int i = (b * 256 + threadIdx.x) * 8;
    if (i >= nWe) return;
    float4 a = *(const float4*)(W + i);
    float4 c = *(const float4*)(W + i + 4);
    f16x8 h;
    h[0] = (half_t)a.x; h[1] = (half_t)a.y; h[2] = (half_t)a.z; h[3] = (half_t)a.w;
    h[4] = (half_t)c.x; h[5] = (half_t)c.y; h[6] = (half_t)c.z; h[7] = (half_t)c.w;
    *(f16x8*)(Wh + i) = h;
  } else {
    int e = (b - nbW) * 256 + threadIdx.x;
    if (e < E) atomicAdd(&deg[row[e]], 1);
  }
}

// ---------------------------------------------------------------------------
// MFMA f16 GEMM v7b: identical structure to v7 but WITHOUT the
// __launch_bounds__ min-waves arg.  v7's (512,2) capped VGPR at 128 while
// acc[4][8] f32x4 alone needs 128 -> everything else spilled to scratch.
// LDS (96KB) already limits to 1 block/CU = 2 waves/SIMD, so the cap bought
// nothing.  Now VGPR can reach ~220: no spills, same occupancy.
// ---------------------------------------------------------------------------
__global__ __launch_bounds__(512) void k_gemm16_v7(const float* __restrict__ X,
                                                   const half_t* __restrict__ Wh,
                                                   const float* __restrict__ bias,
                                                   const float* __restrict__ al,
                                                   const float* __restrict__ ar,
                                                   half_t* __restrict__ Zh,
                                                   float* __restrict__ el,
                                                   float* __restrict__ er,
                                                   int N, int nwg) {
  __shared__ float  As[2][128 * 32];   // 2 x 16 KB, linear
  __shared__ half_t Bs[2][512 * 32];   // 2 x 32 KB, linear
  const int tid  = threadIdx.x;
  const int lane = tid & 63;
  const int wid  = tid >> 6;           // 0..7
  const int wr = wid >> 2, wc = wid & 3;

  // bijective XCD swizzle (m204) -- for Zh/W L2 locality
  int orig = blockIdx.x;
  int xcd = orig & 7;
  int q = nwg >> 3, r = nwg & 7;
  int start = (xcd < r) ? xcd * (q + 1) : r * (q + 1) + (xcd - r) * q;
  int work = start + (orig >> 3);
  const int n0 = work * 128;

  const int rl = lane & 15;
  const int hi16 = lane >> 4;

  // ---- staging maps (kt-invariant) ----
  int a_row[2], a_goff[2];
#pragma unroll
  for (int c = 0; c < 2; c++) {
    int off = c * 8192 + wid * 1024 + lane * 16;
    int rrow = off >> 7;                 // 0..127 (128B per f32 row)
    int sg = (off >> 4) & 7;             // LDS granule in row
    a_row[c]  = rrow;
    a_goff[c] = (sg ^ (rrow & 7)) << 2;  // source f32 offset in row
  }
  int b_row[4], b_goff[4];
#pragma unroll
  for (int c = 0; c < 4; c++) {
    int off = c * 8192 + wid * 1024 + lane * 16;
    int jr = off >> 6;                   // 0..511 (64B per f16 row)
    int g  = (off >> 4) & 3;
    b_row[c]  = jr;
    b_goff[c] = (g ^ ((jr >> 1) & 3)) << 3;  // source half offset in row
  }

#define STAGE(BUF, KT)                                                          \
  do {                                                                          \
    _Pragma("unroll")                                                           \
    for (int c = 0; c < 2; c++) {                                               \
      int an = n0 + a_row[c]; if (an >= N) an = N - 1;                          \
      const float* g = X + (size_t)an * IN_F + (KT) + a_goff[c];                \
      gload_lds16(g, (char*)&As[BUF][0] + c * 8192 + wid * 1024);               \
    }                                                                           \
    _Pragma("unroll")                                                           \
    for (int c = 0; c < 4; c++) {                                               \
      const half_t* g = Wh + (size_t)b_row[c] * IN_F + (KT) + b_goff[c];        \
      gload_lds16(g, (char*)&Bs[BUF][0] + c * 8192 + wid * 1024);               \
    }                                                                           \
  } while (0)

  f32x4 acc[4][8] = {};

  STAGE(0, 0);

#pragma unroll
  for (int ki = 0; ki < 16; ki++) {
    const int cur = ki & 1;
    if (ki < 15) {
      STAGE(cur ^ 1, (ki + 1) * 32);
      asm volatile("s_waitcnt vmcnt(6)" ::: "memory");   // stage ki complete
    } else {
      asm volatile("s_waitcnt vmcnt(0)" ::: "memory");
    }
    __builtin_amdgcn_sched_barrier(0);
    __builtin_amdgcn_s_barrier();

    // ---- fragments (swizzled ds_read) ----
    f16x8 af[4], bf[8];
#pragma unroll
    for (int m = 0; m < 4; m++) {
      int rr = wr * 64 + m * 16 + rl;
      int r7 = rr & 7;
      const char* base = (const char*)&As[cur][0] + rr * 128;
      f32x4 lo = *(const f32x4*)(base + (((hi16 * 2) ^ r7) << 4));
      f32x4 hi = *(const f32x4*)(base + (((hi16 * 2 + 1) ^ r7) << 4));
      f16x8 a;
#pragma unroll
      for (int u = 0; u < 4; u++) { a[u] = (half_t)lo[u]; a[u + 4] = (half_t)hi[u]; }
      af[m] = a;
    }
#pragma unroll
    for (int n = 0; n < 8; n++) {
      int jr = wc * 128 + n * 16 + rl;
      bf[n] = *(const f16x8*)((const char*)&Bs[cur][0] + jr * 64 +
                              ((hi16 ^ ((jr >> 1) & 3)) << 4));
    }
#pragma unroll
    for (int m = 0; m < 4; m++)
#pragma unroll
      for (int n = 0; n < 8; n++)
        acc[m][n] = __builtin_amdgcn_mfma_f32_16x16x32_f16(af[m], bf[n], acc[m][n], 0, 0, 0);

    __builtin_amdgcn_s_barrier();   // all reads of buf[cur] done before restage
  }
#undef STAGE

  // ---- epilogue: Zh write + per-head el/er partials ----
  float bv[8], av[8], rv[8];
#pragma unroll
  for (int n = 0; n < 8; n++) {
    int j = wc * 128 + n * 16 + rl;
    bv[n] = bias[j]; av[n] = al[j]; rv[n] = ar[j];
  }

  float partl[4][4], partr[4][4];
#pragma unroll
  for (int m = 0; m < 4; m++)
#pragma unroll
    for (int qq = 0; qq < 4; qq++) { partl[m][qq] = 0.f; partr[m][qq] = 0.f; }

#pragma unroll
  for (int n = 0; n < 8; n++) {
    int j = wc * 128 + n * 16 + rl;
#pragma unroll
    for (int m = 0; m < 4; m++) {
      int rbase = n0 + wr * 64 + m * 16 + hi16 * 4;
#pragma unroll
      for (int qq = 0; qq < 4; qq++) {
        float v = acc[m][n][qq] + bv[n];
        int nrow = rbase + qq;
        if (nrow < N) Zh[(size_t)nrow * OH + j] = (half_t)v;
        partl[m][qq] = fmaf(v, av[n], partl[m][qq]);
        partr[m][qq] = fmaf(v, rv[n], partr[m][qq]);
      }
    }
  }
  const int h = rl & 7;
#pragma unroll
  for (int m = 0; m < 4; m++) {
#pragma unroll
    for (int qq = 0; qq < 4; qq++) {
      float pl = partl[m][qq], pr = partr[m][qq];
      pl += __shfl_xor(pl, 8);    // fold rl and rl+8 (same head)
      pr += __shfl_xor(pr, 8);
      if (rl < 8) {
        int nrow = n0 + wr * 64 + m * 16 + hi16 * 4 + qq;
        if (nrow < N) {
          atomicAdd(&el[(size_t)nrow * NH + h], pl);
          atomicAdd(&er[(size_t)nrow * NH + h], pr);
        }
      }
    }
  }
}

// ---------------------------------------------------------------------------
// CSR build
// ---------------------------------------------------------------------------
#define SCAN_B 1024
__global__ __launch_bounds__(SCAN_B) void k_scan1(const int* __restrict__ deg,
                                                  int* __restrict__ off,
                                                  int* __restrict__ sums, int N) {
  __shared__ int s[SCAN_B];
  int tid = threadIdx.x;
  int g = blockIdx.x * SCAN_B + tid;
  int v = (g < N) ? deg[g] : 0;
  s[tid] = v;
  __syncthreads();
  for (int o = 1; o < SCAN_B; o <<= 1) {
    int t = (tid >= o) ? s[tid - o] : 0;
    __syncthreads();
    s[tid] += t;
    __syncthreads();
  }
  if (g < N) off[g] = s[tid] - v;
  if (tid == SCAN_B - 1) sums[blockIdx.x] = s[tid];
}

__global__ __launch_bounds__(SCAN_B) void k_scan3(int* __restrict__ off,
                                                  int* __restrict__ cursor,
                                                  const int* __restrict__ sums,
                                                  int nb, int N, int E) {
  __shared__ int sboff;
  int tid = threadIdx.x;
  if (tid < 64) {
    int v = (tid < nb && tid < (int)blockIdx.x) ? sums[tid] : 0;
#pragma unroll
    for (int s = 1; s < 64; s <<= 1) v += __shfl_xor(v, s);
    if (tid == 0) sboff = v;
  }
  __syncthreads();
  int g = blockIdx.x * SCAN_B + tid;
  if (g < N) {
    int v = off[g] + sboff;
    off[g] = v;
    cursor[g] = v;
  }
  if (g == 0) off[N] = E;
}

__global__ void k_fill(const int* __restrict__ row, const int* __restrict__ col,
                       int* __restrict__ cursor, int* __restrict__ colS, int E) {
  int e = blockIdx.x * blockDim.x + threadIdx.x;
  if (e < E) {
    int r = row[e];
    int p = atomicAdd(&cursor[r], 1);
    colS[p] = col[e];
  }
}

// ---------------------------------------------------------------------------
// Fused edge-softmax + aggregation (NT store for out, NT load for colS)
// ---------------------------------------------------------------------------
__global__ __launch_bounds__(256) void k_attagg(const half_t* __restrict__ Zh,
                                                const float* __restrict__ el,
                                                const float* __restrict__ er,
                                                const int* __restrict__ off,
                                                const int* __restrict__ colS,
                                                float* __restrict__ out, int N) {
  __shared__ float wts[4][64][NH];   // 8 KB
  __shared__ int   cls[4][64];       // 1 KB
  int wid = threadIdx.x >> 6, lane = threadIdx.x & 63;
  int i = blockIdx.x * 4 + wid;
  if (i >= N) return;
  int s = off[i], t = off[i + 1];
  int deg = t - s;

  float eli[8];
  {
    const float4* e4 = (const float4*)(el + (size_t)i * NH);
    float4 a = e4[0], b = e4[1];
    eli[0] = a.x; eli[1] = a.y; eli[2] = a.z; eli[3] = a.w;
    eli[4] = b.x; eli[5] = b.y; eli[6] = b.z; eli[7] = b.w;
  }

  float m[8], ehs[8];
  int csave = 0;
#pragma unroll
  for (int h = 0; h < 8; h++) m[h] = -1e30f;
  for (int p = s + lane; p < t; p += 64) {
    int c = __builtin_nontemporal_load(&colS[p]);
    csave = c;
    const float4* e4 = (const float4*)(er + (size_t)c * NH);
    float4 ea = e4[0], eb = e4[1];
    float ev[8] = {ea.x, ea.y, ea.z, ea.w, eb.x, eb.y, eb.z, eb.w};
#pragma unroll
    for (int h = 0; h < 8; h++) {
      float eh = eli[h] + ev[h];
      eh = (eh > 0.f) ? eh : 0.01f * eh;
      ehs[h] = eh;
      m[h] = fmaxf(m[h], eh);
    }
  }
#pragma unroll
  for (int st = 1; st < 64; st <<= 1)
#pragma unroll
    for (int h = 0; h < 8; h++) m[h] = fmaxf(m[h], __shfl_xor(m[h], st));

  float acc[8], den[8];
#pragma unroll
  for (int h = 0; h < 8; h++) { acc[h] = 0.f; den[h] = 0.f; }

  for (int base = s; base < t; base += 64) {
    int p = base + lane;
    if (p < t) {
      int c;
      float eh[8];
      if (deg <= 64) {
        c = csave;
#pragma unroll
        for (int h = 0; h < 8; h++) eh[h] = ehs[h];
      } else {
        c = __builtin_nontemporal_load(&colS[p]);
        const float4* e4 = (const float4*)(er + (size_t)c * NH);
        float4 ea = e4[0], eb = e4[1];
        float ev[8] = {ea.x, ea.y, ea.z, ea.w, eb.x, eb.y, eb.z, eb.w};
#pragma unroll
        for (int h = 0; h < 8; h++) {
          float e2 = eli[h] + ev[h];
          eh[h] = (e2 > 0.f) ? e2 : 0.01f * e2;
        }
      }
      cls[wid][lane] = c;
#pragma unroll
      for (int h = 0; h < 8; h++) {
        float pr = __expf(eh[h] - m[h]);
        den[h] += pr;
        wts[wid][lane][h] = pr;
      }
    }
    int cnt = t - base; if (cnt > 64) cnt = 64;

    int e = 0;
    for (; e + 4 <= cnt; e += 4) {
      int c0 = cls[wid][e + 0], c1 = cls[wid][e + 1];
      int c2 = cls[wid][e + 2], c3 = cls[wid][e + 3];
      f16x8 z0 = *(const f16x8*)(Zh + (size_t)c0 * OH + lane * 8);
      f16x8 z1 = *(const f16x8*)(Zh + (size_t)c1 * OH + lane * 8);
      f16x8 z2 = *(const f16x8*)(Zh + (size_t)c2 * OH + lane * 8);
      f16x8 z3 = *(const f16x8*)(Zh + (size_t)c3 * OH + lane * 8);
      const float* w0 = &wts[wid][e + 0][0];
      const float* w1 = &wts[wid][e + 1][0];
      const float* w2 = &wts[wid][e + 2][0];
      const float* w3 = &wts[wid][e + 3][0];
#pragma unroll
      for (int h = 0; h < 8; h++) {
        acc[h] = fmaf(w0[h], (float)z0[h], acc[h]);
        acc[h] = fmaf(w1[h], (float)z1[h], acc[h]);
        acc[h] = fmaf(w2[h], (float)z2[h], acc[h]);
        acc[h] = fmaf(w3[h], (float)z3[h], acc[h]);
      }
    }
    for (; e < cnt; e++) {
      int c = cls[wid][e];
      f16x8 z = *(const f16x8*)(Zh + (size_t)c * OH + lane * 8);
      const float* w = &wts[wid][e][0];
#pragma unroll
      for (int h = 0; h < 8; h++) acc[h] = fmaf(w[h], (float)z[h], acc[h]);
    }
  }

#pragma unroll
  for (int st = 1; st < 64; st <<= 1)
#pragma unroll
    for (int h = 0; h < 8; h++) den[h] += __shfl_xor(den[h], st);

  f32x4 o0, o1;
  o0[0] = acc[0] / den[0]; o0[1] = acc[1] / den[1];
  o0[2] = acc[2] / den[2]; o0[3] = acc[3] / den[3];
  o1[0] = acc[4] / den[4]; o1[1] = acc[5] / den[5];
  o1[2] = acc[6] / den[6]; o1[3] = acc[7] / den[7];
  __builtin_nontemporal_store(o0, (f32x4*)(out + (size_t)i * OH + lane * 8));
  __builtin_nontemporal_store(o1, (f32x4*)(out + (size_t)i * OH + lane * 8 + 4));
}

// ---------------------------------------------------------------------------
extern "C" void kernel_launch(void* const* d_in, const int* in_sizes, int n_in,
                              void* d_out, int out_size, void* d_ws, size_t ws_size,
                              hipStream_t stream) {
  const float* X    = (const float*)d_in[0];
  const float* W    = (const float*)d_in[1];
  const float* bias = (const float*)d_in[2];
  const float* a_l  = (const float*)d_in[3];
  const float* a_r  = (const float*)d_in[4];
  const int*   row  = (const int*)d_in[5];
  const int*   col  = (const int*)d_in[6];
  float* out = (float*)d_out;

  const int N = in_sizes[0] / IN_F;   // 50000
  const int E = in_sizes[5];          // 850000
  const int nWe = OH * IN_F;

  auto align_up = [](size_t v) { return (v + 255) & ~(size_t)255; };
  char* p = (char*)d_ws;
  half_t* Wh    = (half_t*)p; p += align_up((size_t)nWe * 2);
  half_t* Zh    = (half_t*)p; p += align_up((size_t)N * OH * 2);
  float* el     = (float*)p;  p += (size_t)N * NH * 4;        // el/er contiguous
  float* er     = (float*)p;  p += align_up((size_t)N * NH * 4);
  int*   deg    = (int*)p;    p += align_up((size_t)N * 4);
  int*   off    = (int*)p;    p += align_up((size_t)(N + 1) * 4);
  int*   cursor = (int*)p;    p += align_up((size_t)N * 4);
  int*   sums   = (int*)p;    p += align_up((size_t)64 * 4);
  int*   colS   = (int*)p;    p += align_up((size_t)E * 4);
  (void)ws_size; (void)n_in; (void)out_size;

  const int nb = (N + SCAN_B - 1) / SCAN_B;

  hipMemsetAsync(deg, 0, (size_t)N * 4, stream);
  hipMemsetAsync(el, 0, (size_t)2 * N * NH * 4, stream);

  // fused castW + degree histogram
  const int nbW = (nWe / 8 + 255) / 256;
  const int nbH = (E + 255) / 256;
  hipLaunchKernelGGL(k_prep, dim3(nbW + nbH), dim3(256), 0, stream,
                     W, Wh, nWe, row, deg, E, nbW);

  // full-width MFMA GEMM (X read once per panel) + el/er epilogue
  const int nwg = (N + 127) / 128;
  hipLaunchKernelGGL(k_gemm16_v7, dim3(nwg), dim3(512), 0, stream,
                     X, Wh, bias, a_l, a_r, Zh, el, er, N, nwg);

  // CSR build
  hipLaunchKernelGGL(k_scan1, dim3(nb), dim3(SCAN_B), 0, stream, deg, off, sums, N);
  hipLaunchKernelGGL(k_scan3, dim3(nb), dim3(SCAN_B), 0, stream,
                     off, cursor, sums, nb, N, E);
  hipLaunchKernelGGL(k_fill, dim3((E + 255) / 256), dim3(256), 0, stream,
                     row, col, cursor, colS, E);

  // fused softmax + aggregation
  hipLaunchKernelGGL(k_attagg, dim3((N + 3) / 4), dim3(256), 0, stream,
                     Zh, el, er, off, colS, out, N);
}